// Round 3
// baseline (1501.846 us; speedup 1.0000x reference)
//
#include <hip/hip_runtime.h>
#include <hip/hip_bf16.h>

#define B_ROWS 2048
#define P_ROWS 65536
#define D_DIM  1024
#define L_DIM  32
#define BM 128
#define BN 128
#define BK 64
#define NCHUNK (P_ROWS / BN)   // 512
#define KTILES (D_DIM / BK)    // 16
#define NEG_INF (-3.0e38f)

typedef __attribute__((ext_vector_type(8))) short bf16x8;
typedef __attribute__((ext_vector_type(4))) float f32x4;

// async global->LDS, 16B per lane; LDS dest = wave-uniform base + lane*16
__device__ __forceinline__ void gl16(const void* g, void* l) {
  __builtin_amdgcn_global_load_lds(
      (__attribute__((address_space(1))) void*)const_cast<void*>(g),
      (__attribute__((address_space(3))) void*)l, 16, 0, 0);
}

// RNE float->bf16 (inputs are finite normals; no NaN path needed)
__device__ __forceinline__ unsigned short f2bf(float f) {
  unsigned u = __builtin_bit_cast(unsigned, f);
  unsigned r = u + 0x7fffu + ((u >> 16) & 1u);
  return (unsigned short)(r >> 16);
}

// ---------------------------------------------------------------------------
// Row L2-normalize: writes bf16 normalized rows + fp64 inverse norms.
// One block per row, 256 threads, 1 float4 each (D=1024).
// ---------------------------------------------------------------------------
__global__ __launch_bounds__(256) void norm_rows(
    const float* __restrict__ src, unsigned short* __restrict__ bfo,
    double* __restrict__ inv_out) {
  int row = blockIdx.x, t = threadIdx.x;
  const float4* s4 = (const float4*)(src + (size_t)row * D_DIM);
  float4 v = s4[t];
  double ss = (double)v.x * v.x + (double)v.y * v.y +
              (double)v.z * v.z + (double)v.w * v.w;
  #pragma unroll
  for (int o = 32; o; o >>= 1) ss += __shfl_down(ss, o);
  __shared__ double red[4];
  __shared__ double bcast;
  if ((t & 63) == 0) red[t >> 6] = ss;
  __syncthreads();
  if (t == 0) {
    double tot = red[0] + red[1] + red[2] + red[3];
    double inv = 1.0 / fmax(sqrt(tot), 1e-12);
    inv_out[row] = inv;
    bcast = inv;
  }
  __syncthreads();
  float sc = (float)bcast;
  ushort4 pk;
  pk.x = f2bf(v.x * sc); pk.y = f2bf(v.y * sc);
  pk.z = f2bf(v.z * sc); pk.w = f2bf(v.w * sc);
  ((ushort4*)(bfo + (size_t)row * D_DIM))[t] = pk;
}

// ---------------------------------------------------------------------------
// bf16 MFMA GEMM (128x128 tile, BK=64) with fused per-row top-8 over the
// 128-col chunk. Candidates go to cval/cidx [B][NCHUNK][8].
// Grid: 8192 blocks, row-tile fastest (16 blocks share one bank panel).
// ---------------------------------------------------------------------------
__global__ __launch_bounds__(256) void gemm_topk(
    const unsigned short* __restrict__ Qb, const unsigned short* __restrict__ Pb,
    float* __restrict__ cval, int* __restrict__ cidx) {
  int rt = blockIdx.x & 15;   // row tile 0..15
  int ct = blockIdx.x >> 4;   // col tile 0..511
  int row0 = rt * BM, col0 = ct * BN;
  int tid = threadIdx.x;
  int lane = tid & 63, w = tid >> 6;
  int wm = w >> 1, wn = w & 1;      // wave quadrant (64x64)

  __shared__ union {
    struct { unsigned char a[BM * BK * 2]; unsigned char b[BN * BK * 2]; } st; // 32 KB
    float sim[64 * 132];                                                        // 33 KB
  } lds;

  f32x4 acc[4][4];
  #pragma unroll
  for (int i = 0; i < 4; i++)
    #pragma unroll
    for (int j = 0; j < 4; j++) { f32x4 z = {0.f, 0.f, 0.f, 0.f}; acc[i][j] = z; }

  // staging geometry: per gl16 call a wave covers 8 rows x 128B.
  // XOR-swizzle: element at LDS byte (row*128 + b) comes from global byte-col
  // b ^ ((row&7)<<4); reads apply the same XOR -> conflict-free ds_read_b128.
  int srow = w * 8 + (lane >> 3);        // row within 32-row group
  int js = (lane & 7) ^ (lane >> 3);     // swizzled 16B chunk within the row
  int rsub = lane & 15;
  int ko = lane >> 4;                    // k sub-chunk 0..3

  for (int kt = 0; kt < KTILES; kt++) {
    if (kt) __syncthreads();             // previous tile's reads done
    #pragma unroll
    for (int it = 0; it < 4; it++) {
      int rl = it * 32 + srow;
      gl16(Qb + (size_t)(row0 + rl) * D_DIM + kt * BK + js * 8,
           lds.st.a + (it * 32 + w * 8) * 128);
      gl16(Pb + (size_t)(col0 + rl) * D_DIM + kt * BK + js * 8,
           lds.st.b + (it * 32 + w * 8) * 128);
    }
    asm volatile("s_waitcnt vmcnt(0)" ::: "memory");
    __syncthreads();

    #pragma unroll
    for (int ks = 0; ks < 2; ks++) {
      bf16x8 af[4], bfr[4];
      int cb = ks * 64 + ko * 16;
      #pragma unroll
      for (int mi = 0; mi < 4; mi++) {
        int r = wm * 64 + mi * 16 + rsub;
        af[mi] = *(const bf16x8*)(lds.st.a + r * 128 + (cb ^ ((r & 7) << 4)));
      }
      #pragma unroll
      for (int ni = 0; ni < 4; ni++) {
        int r = wn * 64 + ni * 16 + rsub;
        bfr[ni] = *(const bf16x8*)(lds.st.b + r * 128 + (cb ^ ((r & 7) << 4)));
      }
      #pragma unroll
      for (int mi = 0; mi < 4; mi++)
        #pragma unroll
        for (int ni = 0; ni < 4; ni++)
          acc[mi][ni] = __builtin_amdgcn_mfma_f32_16x16x32_bf16(
              af[mi], bfr[ni], acc[mi][ni], 0, 0, 0);
    }
  }

  // Epilogue: two 64-row passes through the LDS union; per-row top-8 of 128.
  for (int rh = 0; rh < 2; rh++) {
    __syncthreads();
    if (wm == rh) {
      #pragma unroll
      for (int mi = 0; mi < 4; mi++) {
        int rb = mi * 16 + ko * 4;   // C/D layout: row=(lane>>4)*4+reg, col=lane&15
        #pragma unroll
        for (int ni = 0; ni < 4; ni++) {
          int c = wn * 64 + ni * 16 + rsub;
          f32x4 vv = acc[mi][ni];
          lds.sim[(rb + 0) * 132 + c] = vv[0];
          lds.sim[(rb + 1) * 132 + c] = vv[1];
          lds.sim[(rb + 2) * 132 + c] = vv[2];
          lds.sim[(rb + 3) * 132 + c] = vv[3];
        }
      }
    }
    __syncthreads();
    if (tid < 64) {
      const float4* rp = (const float4*)(lds.sim + tid * 132);
      float tv[8]; int ti[8];
      #pragma unroll
      for (int j = 0; j < 8; j++) { tv[j] = NEG_INF; ti[j] = 0; }
      float mn = NEG_INF; int mnp = 0;
      for (int jj = 0; jj < 32; jj++) {
        float4 q4 = rp[jj];
        float vals[4] = {q4.x, q4.y, q4.z, q4.w};
        #pragma unroll
        for (int e = 0; e < 4; e++) {
          float v = vals[e];
          if (v > mn) {  // strict '>' keeps lower col index on ties
            #pragma unroll
            for (int s = 0; s < 8; s++)
              if (s == mnp) { tv[s] = v; ti[s] = jj * 4 + e; }
            mn = tv[0]; mnp = 0;
            #pragma unroll
            for (int s = 1; s < 8; s++)
              if (tv[s] < mn) { mn = tv[s]; mnp = s; }
          }
        }
      }
      int grow = row0 + rh * 64 + tid;
      size_t base = ((size_t)grow * NCHUNK + ct) * 8;
      #pragma unroll
      for (int j = 0; j < 8; j++) {
        cval[base + j] = tv[j];
        cidx[base + j] = col0 + ti[j];
      }
    }
  }
}

// ---------------------------------------------------------------------------
// Per row: top-16 of 4096 candidates (bf16-level values), fp64 refinement,
// exact top-8, softmax(T=0.1), label gather, stats. One block per row.
// ---------------------------------------------------------------------------
__global__ __launch_bounds__(256) void finalize(
    const float* __restrict__ cval, const int* __restrict__ cidx,
    const float* __restrict__ emb, const float* __restrict__ proto,
    const double* __restrict__ qinv, const double* __restrict__ pinv,
    const float* __restrict__ labels, float* __restrict__ out) {
  int row = blockIdx.x, tid = threadIdx.x;
  int lane = tid & 63, w = tid >> 6;
  const float* cv = cval + (size_t)row * (NCHUNK * 8);
  const int* ci = cidx + (size_t)row * (NCHUNK * 8);

  float lv[16]; int li[16];
  #pragma unroll
  for (int j = 0; j < 16; j++) { lv[j] = cv[j * 256 + tid]; li[j] = ci[j * 256 + tid]; }

  __shared__ float rwv[4]; __shared__ int rwi[4];
  __shared__ int seli_s[16];
  __shared__ int winner;
  __shared__ double refined_s[16];
  __shared__ float wts_s[8]; __shared__ float top_v[8]; __shared__ int top_i[8];

  for (int it = 0; it < 16; it++) {
    float bv = NEG_INF; int bi = -1;
    #pragma unroll
    for (int j = 0; j < 16; j++)
      if (lv[j] > bv || (lv[j] == bv && (unsigned)li[j] < (unsigned)bi)) {
        bv = lv[j]; bi = li[j];
      }
    #pragma unroll
    for (int o = 32; o; o >>= 1) {
      float ov = __shfl_down(bv, o); int oi = __shfl_down(bi, o);
      if (ov > bv || (ov == bv && (unsigned)oi < (unsigned)bi)) { bv = ov; bi = oi; }
    }
    if (lane == 0) { rwv[w] = bv; rwi[w] = bi; }
    __syncthreads();
    if (tid == 0) {
      float v0 = rwv[0]; int i0 = rwi[0];
      for (int k = 1; k < 4; k++)
        if (rwv[k] > v0 || (rwv[k] == v0 && (unsigned)rwi[k] < (unsigned)i0)) {
          v0 = rwv[k]; i0 = rwi[k];
        }
      seli_s[it] = i0; winner = i0;
    }
    __syncthreads();
    int wi = winner;
    #pragma unroll
    for (int j = 0; j < 16; j++) if (li[j] == wi) lv[j] = NEG_INF;
  }

  // fp64 refinement: wave w handles candidates 4w..4w+3
  const float4* e4 = (const float4*)(emb + (size_t)row * D_DIM);
  double qiv = qinv[row];
  for (int q = 0; q < 4; q++) {
    int slot = w * 4 + q;
    int gi = seli_s[slot];
    const float4* p4 = (const float4*)(proto + (size_t)gi * D_DIM);
    double s = 0.0;
    #pragma unroll
    for (int c = 0; c < 4; c++) {
      float4 a = e4[c * 64 + lane]; float4 b = p4[c * 64 + lane];
      s += (double)a.x * b.x + (double)a.y * b.y +
           (double)a.z * b.z + (double)a.w * b.w;
    }
    #pragma unroll
    for (int o = 32; o; o >>= 1) s += __shfl_down(s, o);
    if (lane == 0) refined_s[slot] = s * qiv * pinv[gi];
  }
  __syncthreads();

  if (tid == 0) {
    // exact top-8 of the 16 refined sims (tie -> lower prototype index)
    for (int j = 0; j < 8; j++) {
      double bvv = -1e300; int bii = -1; int bslot = 0;
      for (int t = 0; t < 16; t++) {
        double v = refined_s[t]; int gi2 = seli_s[t];
        if (v > bvv || (v == bvv && (unsigned)gi2 < (unsigned)bii)) {
          bvv = v; bii = gi2; bslot = t;
        }
      }
      refined_s[bslot] = -1e300;
      top_v[j] = (float)bvv; top_i[j] = bii;
    }
    float mx = top_v[0];
    float e[8]; float s = 0.f; float sum8 = 0.f;
    #pragma unroll
    for (int j = 0; j < 8; j++) {
      e[j] = expf((top_v[j] - mx) * 10.0f);  // /T, T=0.1
      s += e[j]; sum8 += top_v[j];
    }
    #pragma unroll
    for (int j = 0; j < 8; j++) wts_s[j] = e[j] / s;
    out[B_ROWS * L_DIM + row * 2 + 0] = top_v[0];        // max
    out[B_ROWS * L_DIM + row * 2 + 1] = sum8 * 0.125f;   // mean
  }
  __syncthreads();
  if (tid < L_DIM) {
    float acc = 0.f;
    #pragma unroll
    for (int j = 0; j < 8; j++)
      acc += wts_s[j] * labels[(size_t)top_i[j] * L_DIM + tid];
    out[(size_t)row * L_DIM + tid] = acc;
  }
}

// ---------------------------------------------------------------------------
extern "C" void kernel_launch(void* const* d_in, const int* in_sizes, int n_in,
                              void* d_out, int out_size, void* d_ws, size_t ws_size,
                              hipStream_t stream) {
  const float* emb = (const float*)d_in[0];     // [2048,1024]
  const float* proto = (const float*)d_in[1];   // [65536,1024]
  const float* labels = (const float*)d_in[2];  // [65536,32]
  float* out = (float*)d_out;

  char* ws = (char*)d_ws;
  size_t off = 0;
  unsigned short* qbf = (unsigned short*)(ws + off); off += (size_t)B_ROWS * D_DIM * 2;  // 4 MB
  unsigned short* pbf = (unsigned short*)(ws + off); off += (size_t)P_ROWS * D_DIM * 2;  // 128 MB
  double* qinv = (double*)(ws + off); off += (size_t)B_ROWS * 8;                          // 16 KB
  double* pinv = (double*)(ws + off); off += (size_t)P_ROWS * 8;                          // 512 KB
  float* cval = (float*)(ws + off); off += (size_t)B_ROWS * NCHUNK * 8 * 4;               // 32 MB
  int* cidx = (int*)(ws + off); off += (size_t)B_ROWS * NCHUNK * 8 * 4;                   // 32 MB
  // total ~197 MB

  norm_rows<<<B_ROWS, 256, 0, stream>>>(emb, qbf, qinv);
  norm_rows<<<P_ROWS, 256, 0, stream>>>(proto, pbf, pinv);
  gemm_topk<<<(B_ROWS / BM) * (P_ROWS / BN), 256, 0, stream>>>(qbf, pbf, cval, cidx);
  finalize<<<B_ROWS, 256, 0, stream>>>(cval, cidx, emb, proto, qinv, pinv, labels, out);
}

// Round 5
// 999.558 us; speedup vs baseline: 1.5025x; 1.5025x over previous
//
#include <hip/hip_runtime.h>
#include <hip/hip_bf16.h>

#define B_ROWS 2048
#define P_ROWS 65536
#define D_DIM  1024
#define L_DIM  32
#define BM 128
#define BN 128
#define BK 64
#define NCHUNK (P_ROWS / BN)   // 512
#define KTILES (D_DIM / BK)    // 16
#define CPC 4                  // candidates per 128-col chunk
#define NEG_INF (-3.0e38f)

typedef __attribute__((ext_vector_type(8))) short bf16x8;
typedef __attribute__((ext_vector_type(4))) float f32x4;

// async global->LDS, 16B per lane; LDS dest = wave-uniform base + lane*16
__device__ __forceinline__ void gl16(const void* g, void* l) {
  __builtin_amdgcn_global_load_lds(
      (__attribute__((address_space(1))) void*)const_cast<void*>(g),
      (__attribute__((address_space(3))) void*)l, 16, 0, 0);
}

// RNE float->bf16 (inputs are finite normals; no NaN path needed)
__device__ __forceinline__ unsigned short f2bf(float f) {
  unsigned u = __builtin_bit_cast(unsigned, f);
  unsigned r = u + 0x7fffu + ((u >> 16) & 1u);
  return (unsigned short)(r >> 16);
}

// ---------------------------------------------------------------------------
// Row L2-normalize: writes bf16 normalized rows + fp64 inverse norms.
// ---------------------------------------------------------------------------
__global__ __launch_bounds__(256) void norm_rows(
    const float* __restrict__ src, unsigned short* __restrict__ bfo,
    double* __restrict__ inv_out) {
  int row = blockIdx.x, t = threadIdx.x;
  const float4* s4 = (const float4*)(src + (size_t)row * D_DIM);
  float4 v = s4[t];
  double ss = (double)v.x * v.x + (double)v.y * v.y +
              (double)v.z * v.z + (double)v.w * v.w;
  #pragma unroll
  for (int o = 32; o; o >>= 1) ss += __shfl_down(ss, o);
  __shared__ double red[4];
  __shared__ double bcast;
  if ((t & 63) == 0) red[t >> 6] = ss;
  __syncthreads();
  if (t == 0) {
    double tot = red[0] + red[1] + red[2] + red[3];
    double inv = 1.0 / fmax(sqrt(tot), 1e-12);
    inv_out[row] = inv;
    bcast = inv;
  }
  __syncthreads();
  float sc = (float)bcast;
  ushort4 pk;
  pk.x = f2bf(v.x * sc); pk.y = f2bf(v.y * sc);
  pk.z = f2bf(v.z * sc); pk.w = f2bf(v.w * sc);
  ((ushort4*)(bfo + (size_t)row * D_DIM))[t] = pk;
}

// ---------------------------------------------------------------------------
// bf16 MFMA GEMM (128x128 tile, BK=64), XCD-pinned ct panels, fused per-row
// top-4 candidate extraction in registers (packed val+col keys).
// ---------------------------------------------------------------------------
__global__ __launch_bounds__(256) void gemm_topk(
    const unsigned short* __restrict__ Qb, const unsigned short* __restrict__ Pb,
    float* __restrict__ cval, int* __restrict__ cidx) {
  // XCD-pinned mapping: xcd = bid&7 owns ct in [xcd*64, xcd*64+64);
  // within an XCD, consecutive blocks sweep rt over one Pb panel (L2-resident).
  int bid = blockIdx.x;
  int xcd = bid & 7, s = bid >> 3;
  int ct = xcd * 64 + (s >> 4);   // col tile 0..511
  int rt = s & 15;                // row tile 0..15
  int row0 = rt * BM, col0 = ct * BN;
  int tid = threadIdx.x;
  int lane = tid & 63, w = tid >> 6;
  int wm = w >> 1, wn = w & 1;      // wave quadrant (64x64)

  __shared__ union {
    struct { unsigned char a[BM * BK * 2]; unsigned char b[BN * BK * 2]; } st; // 32 KB
    float mergeK[128 * 8];                                                      // 4 KB
  } lds;

  f32x4 acc[4][4];
  #pragma unroll
  for (int i = 0; i < 4; i++)
    #pragma unroll
    for (int j = 0; j < 4; j++) { f32x4 z = {0.f, 0.f, 0.f, 0.f}; acc[i][j] = z; }

  // staging geometry: per gl16 call a wave covers 8 rows x 128B.
  // XOR-swizzle: LDS[row][c16] = global[row][c16 ^ (row&7)]; reads use same XOR.
  int srow = w * 8 + (lane >> 3);        // row within 32-row group
  int js = (lane & 7) ^ (lane >> 3);     // swizzled 16B chunk within the row
  int rsub = lane & 15;
  int ko = lane >> 4;                    // k sub-chunk 0..3

  for (int kt = 0; kt < KTILES; kt++) {
    if (kt) __syncthreads();             // previous tile's reads done
    #pragma unroll
    for (int it = 0; it < 4; it++) {
      int rl = it * 32 + srow;
      gl16(Qb + (size_t)(row0 + rl) * D_DIM + kt * BK + js * 8,
           lds.st.a + (it * 32 + w * 8) * 128);
      gl16(Pb + (size_t)(col0 + rl) * D_DIM + kt * BK + js * 8,
           lds.st.b + (it * 32 + w * 8) * 128);
    }
    asm volatile("s_waitcnt vmcnt(0)" ::: "memory");
    __syncthreads();

    #pragma unroll
    for (int ks = 0; ks < 2; ks++) {
      bf16x8 af[4], bfr[4];
      int cb = ks * 64 + ko * 16;
      #pragma unroll
      for (int mi = 0; mi < 4; mi++) {
        int r = wm * 64 + mi * 16 + rsub;
        af[mi] = *(const bf16x8*)(lds.st.a + r * 128 + (cb ^ ((r & 7) << 4)));
      }
      #pragma unroll
      for (int ni = 0; ni < 4; ni++) {
        int r = wn * 64 + ni * 16 + rsub;
        bfr[ni] = *(const bf16x8*)(lds.st.b + r * 128 + (cb ^ ((r & 7) << 4)));
      }
      #pragma unroll
      for (int mi = 0; mi < 4; mi++)
        #pragma unroll
        for (int ni = 0; ni < 4; ni++)
          acc[mi][ni] = __builtin_amdgcn_mfma_f32_16x16x32_bf16(
              af[mi], bfr[ni], acc[mi][ni], 0, 0, 0);
    }
  }

  // ---- Epilogue: all-wave register extraction of per-row top-4 per half ----
  // Packed key: bits(val+2.0) with low 7 mantissa bits = 127 - col_local
  // (monotone in val, quantization ~3e-5 << 2e-2 candidate margins; larger
  // key = larger val then lower col). col_local = 127 - (key & 0x7F).
  __syncthreads();   // staging LDS -> merge buffer reuse

  unsigned colb[4];
  #pragma unroll
  for (int ni = 0; ni < 4; ni++)
    colb[ni] = (unsigned)(127 - (wn * 64 + ni * 16 + rsub));

  #pragma unroll
  for (int mi = 0; mi < 4; mi++) {
    #pragma unroll
    for (int k = 0; k < 4; k++) {
      float key[4];
      #pragma unroll
      for (int ni = 0; ni < 4; ni++) {
        unsigned kb = (__builtin_bit_cast(unsigned, acc[mi][ni][k] + 2.0f)
                       & 0xFFFFFF80u) | colb[ni];
        key[ni] = __builtin_bit_cast(float, kb);
      }
      int r128 = wm * 64 + mi * 16 + ko * 4 + k;   // row within 128-tile
      #pragma unroll
      for (int it = 0; it < 4; it++) {
        float m = fmaxf(fmaxf(key[0], key[1]), fmaxf(key[2], key[3]));
        m = fmaxf(m, __shfl_xor(m, 1));
        m = fmaxf(m, __shfl_xor(m, 2));
        m = fmaxf(m, __shfl_xor(m, 4));
        m = fmaxf(m, __shfl_xor(m, 8));
        if (rsub == it) lds.mergeK[r128 * 8 + wn * 4 + it] = m;
        #pragma unroll
        for (int ni = 0; ni < 4; ni++)
          if (key[ni] == m) key[ni] = NEG_INF;
      }
    }
  }
  __syncthreads();

  // merge the two 64-col halves: top-4 of 8 keys per row, emit candidates
  if (tid < 128) {
    float k8[8];
    #pragma unroll
    for (int j = 0; j < 8; j++) k8[j] = lds.mergeK[tid * 8 + j];
    float outv[4]; int outi[4];
    #pragma unroll
    for (int it = 0; it < 4; it++) {
      float m = k8[0];
      #pragma unroll
      for (int j = 1; j < 8; j++) m = fmaxf(m, k8[j]);
      #pragma unroll
      for (int j = 0; j < 8; j++) if (k8[j] == m) k8[j] = NEG_INF;
      outv[it] = m;
      outi[it] = col0 + 127 - (int)(__builtin_bit_cast(unsigned, m) & 0x7Fu);
    }
    size_t base = ((size_t)(row0 + tid) * NCHUNK + ct) * CPC;
    *(float4*)(cval + base) = make_float4(outv[0], outv[1], outv[2], outv[3]);
    *(int4*)(cidx + base) = make_int4(outi[0], outi[1], outi[2], outi[3]);
  }
}

// ---------------------------------------------------------------------------
// Per row: top-16 of 2048 candidate keys, fp64 refinement, exact top-8,
// softmax(T=0.1), label gather, stats. One block per row.
// ---------------------------------------------------------------------------
__global__ __launch_bounds__(256) void finalize(
    const float* __restrict__ cval, const int* __restrict__ cidx,
    const float* __restrict__ emb, const float* __restrict__ proto,
    const double* __restrict__ qinv, const double* __restrict__ pinv,
    const float* __restrict__ labels, float* __restrict__ out) {
  int row = blockIdx.x, tid = threadIdx.x;
  int lane = tid & 63, w = tid >> 6;
  const float* cv = cval + (size_t)row * (NCHUNK * CPC);
  const int* ci = cidx + (size_t)row * (NCHUNK * CPC);

  float lv[8]; int li[8];
  #pragma unroll
  for (int j = 0; j < 8; j++) { lv[j] = cv[j * 256 + tid]; li[j] = ci[j * 256 + tid]; }

  __shared__ float rwv[4]; __shared__ int rwi[4];
  __shared__ int seli_s[16];
  __shared__ int winner;
  __shared__ double refined_s[16];
  __shared__ float wts_s[8]; __shared__ float top_v[8]; __shared__ int top_i[8];

  for (int it = 0; it < 16; it++) {
    float bv = NEG_INF; int bi = -1;
    #pragma unroll
    for (int j = 0; j < 8; j++)
      if (lv[j] > bv || (lv[j] == bv && (unsigned)li[j] < (unsigned)bi)) {
        bv = lv[j]; bi = li[j];
      }
    #pragma unroll
    for (int o = 32; o; o >>= 1) {
      float ov = __shfl_down(bv, o); int oi = __shfl_down(bi, o);
      if (ov > bv || (ov == bv && (unsigned)oi < (unsigned)bi)) { bv = ov; bi = oi; }
    }
    if (lane == 0) { rwv[w] = bv; rwi[w] = bi; }
    __syncthreads();
    if (tid == 0) {
      float v0 = rwv[0]; int i0 = rwi[0];
      for (int k = 1; k < 4; k++)
        if (rwv[k] > v0 || (rwv[k] == v0 && (unsigned)rwi[k] < (unsigned)i0)) {
          v0 = rwv[k]; i0 = rwi[k];
        }
      seli_s[it] = i0; winner = i0;
    }
    __syncthreads();
    int wi = winner;
    #pragma unroll
    for (int j = 0; j < 8; j++) if (li[j] == wi) lv[j] = NEG_INF;
  }

  // fp64 refinement: wave w handles candidates 4w..4w+3
  const float4* e4 = (const float4*)(emb + (size_t)row * D_DIM);
  double qiv = qinv[row];
  for (int q = 0; q < 4; q++) {
    int slot = w * 4 + q;
    int gi = seli_s[slot];
    const float4* p4 = (const float4*)(proto + (size_t)gi * D_DIM);
    double ssum = 0.0;
    #pragma unroll
    for (int c = 0; c < 4; c++) {
      float4 a = e4[c * 64 + lane]; float4 b = p4[c * 64 + lane];
      ssum += (double)a.x * b.x + (double)a.y * b.y +
              (double)a.z * b.z + (double)a.w * b.w;
    }
    #pragma unroll
    for (int o = 32; o; o >>= 1) ssum += __shfl_down(ssum, o);
    if (lane == 0) refined_s[slot] = ssum * qiv * pinv[gi];
  }
  __syncthreads();

  if (tid == 0) {
    // exact top-8 of the 16 refined sims (tie -> lower prototype index)
    for (int j = 0; j < 8; j++) {
      double bvv = -1e300; int bii = -1; int bslot = 0;
      for (int t = 0; t < 16; t++) {
        double v = refined_s[t]; int gi2 = seli_s[t];
        if (v > bvv || (v == bvv && (unsigned)gi2 < (unsigned)bii)) {
          bvv = v; bii = gi2; bslot = t;
        }
      }
      refined_s[bslot] = -1e300;
      top_v[j] = (float)bvv; top_i[j] = bii;
    }
    float mx = top_v[0];
    float e[8]; float sm = 0.f; float sum8 = 0.f;
    #pragma unroll
    for (int j = 0; j < 8; j++) {
      e[j] = expf((top_v[j] - mx) * 10.0f);  // /T, T=0.1
      sm += e[j]; sum8 += top_v[j];
    }
    #pragma unroll
    for (int j = 0; j < 8; j++) wts_s[j] = e[j] / sm;
    out[B_ROWS * L_DIM + row * 2 + 0] = top_v[0];        // max
    out[B_ROWS * L_DIM + row * 2 + 1] = sum8 * 0.125f;   // mean
  }
  __syncthreads();
  if (tid < L_DIM) {
    float acc = 0.f;
    #pragma unroll
    for (int j = 0; j < 8; j++)
      acc += wts_s[j] * labels[(size_t)top_i[j] * L_DIM + tid];
    out[(size_t)row * L_DIM + tid] = acc;
  }
}

// ---------------------------------------------------------------------------
extern "C" void kernel_launch(void* const* d_in, const int* in_sizes, int n_in,
                              void* d_out, int out_size, void* d_ws, size_t ws_size,
                              hipStream_t stream) {
  const float* emb = (const float*)d_in[0];     // [2048,1024]
  const float* proto = (const float*)d_in[1];   // [65536,1024]
  const float* labels = (const float*)d_in[2];  // [65536,32]
  float* out = (float*)d_out;

  char* ws = (char*)d_ws;
  size_t off = 0;
  unsigned short* qbf = (unsigned short*)(ws + off); off += (size_t)B_ROWS * D_DIM * 2;  // 4 MB
  unsigned short* pbf = (unsigned short*)(ws + off); off += (size_t)P_ROWS * D_DIM * 2;  // 128 MB
  double* qinv = (double*)(ws + off); off += (size_t)B_ROWS * 8;                          // 16 KB
  double* pinv = (double*)(ws + off); off += (size_t)P_ROWS * 8;                          // 512 KB
  float* cval = (float*)(ws + off); off += (size_t)B_ROWS * NCHUNK * CPC * 4;             // 16 MB
  int* cidx = (int*)(ws + off); off += (size_t)B_ROWS * NCHUNK * CPC * 4;                 // 16 MB
  // total ~165 MB

  norm_rows<<<B_ROWS, 256, 0, stream>>>(emb, qbf, qinv);
  norm_rows<<<P_ROWS, 256, 0, stream>>>(proto, pbf, pinv);
  gemm_topk<<<(B_ROWS / BM) * (P_ROWS / BN), 256, 0, stream>>>(qbf, pbf, cval, cidx);
  finalize<<<B_ROWS, 256, 0, stream>>>(cval, cidx, emb, proto, qinv, pinv, labels, out);
}